// Round 10
// baseline (302.129 us; speedup 1.0000x reference)
//
#include <hip/hip_runtime.h>
#include <math.h>

typedef __attribute__((ext_vector_type(8))) short short8;
typedef __bf16 bf16x8 __attribute__((ext_vector_type(8)));
typedef __attribute__((ext_vector_type(4))) float f32x4;
typedef __attribute__((ext_vector_type(2))) float f32x2;
typedef __attribute__((ext_vector_type(16))) float f32x16;
typedef __attribute__((ext_vector_type(4))) unsigned uint4v;

__device__ inline short f2bf(float f) {
    unsigned u = __builtin_bit_cast(unsigned, f);
    u += 0x7fff + ((u >> 16) & 1);   // round-to-nearest-even
    return (short)(u >> 16);
}
__device__ inline float gelu_f(float x) {
    return 0.5f * x * (1.f + erff(x * 0.70710678118654752f));
}

// global->LDS direct DMA, 16B per lane. Dest is wave-uniform base; HW writes
// base + lane*16. Source address is per-lane (pre-swizzled for XOR layout).
__device__ inline void gload_lds16(const void* g, void* l) {
    __builtin_amdgcn_global_load_lds(
        (const __attribute__((address_space(1))) unsigned int*)g,
        (__attribute__((address_space(3))) unsigned int*)l, 16, 0, 0);
}

// ---------------------------------------------------------------------------
// Weight prep only. 2048 blocks, all 6 weight transposes to bf16 [N][K].
// ---------------------------------------------------------------------------
__global__ __launch_bounds__(256) void prep_w(
    const float* __restrict__ Wq1, const float* __restrict__ Wk1,
    const float* __restrict__ Wq2, const float* __restrict__ Wk2,
    const float* __restrict__ Wv,  const float* __restrict__ Wo,
    short* __restrict__ Wq1t, short* __restrict__ Wk1t,
    short* __restrict__ Wq2t, short* __restrict__ Wk2t,
    short* __restrict__ Wvt,  short* __restrict__ Wot)
{
    int id = blockIdx.x;
    const float* W; short* Wt; int K, N;
    if (id < 512)       { W = Wq1; Wt = Wq1t; K = 512;  N = 1024; }
    else if (id < 1024) { W = Wk1; Wt = Wk1t; K = 512;  N = 1024; id -= 512; }
    else if (id < 1280) { W = Wq2; Wt = Wq2t; K = 1024; N = 256;  id -= 1024; }
    else if (id < 1536) { W = Wk2; Wt = Wk2t; K = 1024; N = 256;  id -= 1280; }
    else if (id < 1792) { W = Wv;  Wt = Wvt;  K = 512;  N = 512;  id -= 1536; }
    else                { W = Wo;  Wt = Wot;  K = 512;  N = 512;  id -= 1792; }
    int nx = N >> 5;
    int n0 = (id % nx) * 32, k0 = (id / nx) * 32;

    __shared__ float T[32][33];
    int tid = threadIdx.x;
    int r = tid >> 3, c4 = (tid & 7) * 4;
    float4 v4 = *(const float4*)&W[(size_t)(k0 + r) * N + n0 + c4];
    T[r][c4 + 0] = v4.x; T[r][c4 + 1] = v4.y; T[r][c4 + 2] = v4.z; T[r][c4 + 3] = v4.w;
    __syncthreads();
    short4 o;
    o.x = f2bf(T[c4 + 0][r]);
    o.y = f2bf(T[c4 + 1][r]);
    o.z = f2bf(T[c4 + 2][r]);
    o.w = f2bf(T[c4 + 3][r]);
    *(short4*)&Wt[(size_t)(n0 + r) * K + k0 + c4] = o;
}

// ---------------------------------------------------------------------------
// Shared GEMM core — NOW 2-PHASE PREFETCHED (T3-minimum): double-buffered
// LDS; each K-step issues next tile's loads BEFORE computing the current
// tile; one vmcnt(0)+barrier per K-step (was 2 barriers, latency exposed;
// R9 counters: MfmaUtil 9.5%, HBM 11% -> stage-latency-bound).
// Exactly ONE call site per __global__ kernel (R7/R8 lesson).
// om: 0 = bf16 plain, 1 = f32 plain, 2 = kfr frag scatter, 3 = vfr frag
// scatter (exact inverses of the former repack_kv mappings, proven R6).
// AF32: A is raw f32 -> reg-stage + v_cvt_pk_bf16_f32 (RNE) -> ds_write;
// the reg loads are issued with the prefetch and written after vmcnt(0).
// ---------------------------------------------------------------------------
template <int BM, int BN, int AF32>
__device__ __forceinline__ void gemm_core(
    const void* __restrict__ A, const short* __restrict__ B,
    const float* __restrict__ bias, void* __restrict__ C_,
    float scale, int act, int om, int nbn, int N, int K, int L)
{
    constexpr int MT = BM / 32;
    constexpr int NT = BN / 32;
    const int xcd = L & 7;
    const int per = L >> 3;
    const int bn = (per % nbn) * BN;
    const int bm = ((per / nbn) * 8 + xcd) * BM;

    const int tid = threadIdx.x;
    const int w = tid >> 6;
    const int lane = tid & 63;
    const int l15 = lane & 15, quad = lane >> 4;
    const int wm = (w >> 1) * (BM / 2), wn = (w & 1) * (BN / 2);

    __shared__ __align__(16) short As[2][BM * 64];
    __shared__ __align__(16) short Bs[2][BN * 64];

    const float* Af = (const float*)A;
    const short* Ab = (const short*)A;

    float4 xa[BM / 32], ya[BM / 32];   // AF32 in-flight reg staging

    auto stage_issue = [&](int k0, int buf) {
#pragma unroll
        for (int i = 0; i < BM / 32; ++i) {
            int ga = tid + i * 256;
            int row = ga >> 3, g = ga & 7;
            if constexpr (AF32) {
                const float* src = &Af[(size_t)(bm + row) * K + k0 + ((g ^ (row & 7)) * 8)];
                xa[i] = *(const float4*)src;
                ya[i] = *(const float4*)(src + 4);
            } else {
                gload_lds16(&Ab[(size_t)(bm + row) * K + k0 + ((g ^ (row & 7)) * 8)],
                            &As[buf][(i * 256 + w * 64) * 8]);
            }
        }
#pragma unroll
        for (int i = 0; i < BN / 32; ++i) {
            int gb = tid + i * 256;
            int row = gb >> 3, g = gb & 7;
            gload_lds16(&B[(size_t)(bn + row) * K + k0 + ((g ^ (row & 7)) * 8)],
                        &Bs[buf][(i * 256 + w * 64) * 8]);
        }
    };
    auto stage_finish = [&](int buf) {
        asm volatile("s_waitcnt vmcnt(0)");
        if constexpr (AF32) {
#pragma unroll
            for (int i = 0; i < BM / 32; ++i) {
                int ga = tid + i * 256;
                int row = ga >> 3, g = ga & 7;
                unsigned u0, u1, u2, u3;
                asm("v_cvt_pk_bf16_f32 %0, %1, %2" : "=v"(u0) : "v"(xa[i].x), "v"(xa[i].y));
                asm("v_cvt_pk_bf16_f32 %0, %1, %2" : "=v"(u1) : "v"(xa[i].z), "v"(xa[i].w));
                asm("v_cvt_pk_bf16_f32 %0, %1, %2" : "=v"(u2) : "v"(ya[i].x), "v"(ya[i].y));
                asm("v_cvt_pk_bf16_f32 %0, %1, %2" : "=v"(u3) : "v"(ya[i].z), "v"(ya[i].w));
                uint4v u; u[0] = u0; u[1] = u1; u[2] = u2; u[3] = u3;
                *(uint4v*)(void*)&As[buf][row * 64 + g * 8] = u;
            }
        }
    };

    f32x4 acc[MT][NT];
#pragma unroll
    for (int mt = 0; mt < MT; ++mt)
#pragma unroll
        for (int nt = 0; nt < NT; ++nt) acc[mt][nt] = (f32x4){0.f, 0.f, 0.f, 0.f};

    const int ntile = K >> 6;

    // prologue: stage tile 0 into buf 0
    stage_issue(0, 0);
    stage_finish(0);
    __syncthreads();

    int cur = 0;
    for (int t = 0; t < ntile; ++t) {
        const bool has_next = (t + 1 < ntile);
        if (has_next) stage_issue((t + 1) << 6, cur ^ 1);   // prefetch

        const short* Asc = As[cur];
        const short* Bsc = Bs[cur];
#pragma unroll
        for (int ks = 0; ks < 2; ++ks) {
            bf16x8 af[MT], bfr[NT];
#pragma unroll
            for (int t2 = 0; t2 < MT; ++t2) {
                int row = wm + t2 * 16 + l15;
                af[t2] = __builtin_bit_cast(bf16x8,
                    *(const short8*)(const void*)&Asc[row * 64 + (((ks * 4 + quad) ^ (row & 7)) * 8)]);
            }
#pragma unroll
            for (int t2 = 0; t2 < NT; ++t2) {
                int row = wn + t2 * 16 + l15;
                bfr[t2] = __builtin_bit_cast(bf16x8,
                    *(const short8*)(const void*)&Bsc[row * 64 + (((ks * 4 + quad) ^ (row & 7)) * 8)]);
            }
#pragma unroll
            for (int mt = 0; mt < MT; ++mt)
#pragma unroll
                for (int nt = 0; nt < NT; ++nt)
                    acc[mt][nt] = __builtin_amdgcn_mfma_f32_16x16x32_bf16(af[mt], bfr[nt], acc[mt][nt], 0, 0, 0);
        }

        if (has_next) stage_finish(cur ^ 1);   // drain + A cvt/ds_write
        __syncthreads();
        cur ^= 1;
    }

    float bvv[NT];
#pragma unroll
    for (int nt = 0; nt < NT; ++nt) bvv[nt] = bias[bn + wn + nt * 16 + l15];
#pragma unroll
    for (int mt = 0; mt < MT; ++mt)
#pragma unroll
        for (int r = 0; r < 4; ++r) {
            int row = bm + wm + mt * 16 + quad * 4 + r;
#pragma unroll
            for (int nt = 0; nt < NT; ++nt) {
                float v = acc[mt][nt][r] + bvv[nt];
                if (act) v = gelu_f(v);
                v *= scale;
                int col = bn + wn + nt * 16 + l15;
                if (om == 1) {
                    ((float*)C_)[(size_t)row * N + col] = v;
                } else if (om == 2) {
                    // kfr scatter: inverse of repack_kv K-path.
                    int b_ = row >> 12, key = row & 4095;
                    int kt = key >> 6, nt_ = (key >> 5) & 1, l31_ = key & 31;
                    int h_ = col >> 5, kcol = col & 31;
                    int ks_ = kcol >> 4, hi_ = (kcol >> 3) & 1, j_ = kcol & 7;
                    size_t idx = ((((size_t)(b_ * 8 + h_) * 64 + kt) * 4 +
                                   (nt_ * 2 + ks_)) * 64 + (hi_ * 32 + l31_)) * 8 + j_;
                    ((short*)C_)[idx] = f2bf(v);
                } else if (om == 3) {
                    // vfr scatter: inverse of repack_kv V-path.
                    int b_ = row >> 12, key = row & 4095;
                    int kt = key >> 6, keyr = key & 63;
                    int ks_ = keyr >> 4, hi_ = (keyr >> 3) & 1, j_ = keyr & 7;
                    int h_ = col >> 6, dk = col & 63;
                    int dt_ = dk >> 5, l31_ = dk & 31;
                    size_t idx = ((((size_t)(b_ * 8 + h_) * 64 + kt) * 8 +
                                   (dt_ * 4 + ks_)) * 64 + (hi_ * 32 + l31_)) * 8 + j_;
                    ((short*)C_)[idx] = f2bf(v);
                } else {
                    ((short*)C_)[(size_t)row * N + col] = f2bf(v);
                }
            }
        }
}

// ---------------------------------------------------------------------------
// Merged front-end: z=0 q-MLP1, z=1 k-MLP1 (N=1024, GELU), z=2 v-projection
// (N=512, vfr scatter). All BM=BN=128, AF32 staging; ONE gemm_core call site
// (runtime pointer/param select). z=2 uses only 256 of 512 blocks.
// ---------------------------------------------------------------------------
__global__ __launch_bounds__(256) void mega1(
    const float* __restrict__ q, const float* __restrict__ k,
    const float* __restrict__ v,
    const short* __restrict__ Wq1t, const short* __restrict__ Wk1t,
    const short* __restrict__ Wvt,
    const float* __restrict__ bq1, const float* __restrict__ bk1,
    const float* __restrict__ bv,
    short* __restrict__ H1q, short* __restrict__ H1k, short* __restrict__ vfr)
{
    const int z = blockIdx.z;
    if (z == 2 && blockIdx.x >= 256) return;
    const float* A   = z == 2 ? v    : (z == 1 ? k    : q);
    const short* B   = z == 2 ? Wvt  : (z == 1 ? Wk1t : Wq1t);
    const float* bia = z == 2 ? bv   : (z == 1 ? bk1  : bq1);
    void*        C   = z == 2 ? (void*)vfr : (z == 1 ? (void*)H1k : (void*)H1q);
    const int act = z == 2 ? 0 : 1;
    const int om  = z == 2 ? 3 : 0;
    const int nbn = z == 2 ? 4 : 8;
    const int N   = z == 2 ? 512 : 1024;
    gemm_core<128, 128, 1>(A, B, bia, C, 1.f, act, om, nbn, N, 512, blockIdx.x);
}

// MLP layer 2 (q & k): q -> qbb plain (pre-scaled), k -> kfr frag scatter.
// ONE gemm_core call site.
__global__ __launch_bounds__(256) void gemm2k(
    const short* __restrict__ H1q, const short* __restrict__ H1k,
    const short* __restrict__ Wq2t, const short* __restrict__ Wk2t,
    const float* __restrict__ bq2, const float* __restrict__ bk2,
    short* __restrict__ qbb, short* __restrict__ kfr, float qscale)
{
    const int z = blockIdx.z;
    const short* A   = z ? H1k : H1q;
    const short* B   = z ? Wk2t : Wq2t;
    const float* bia = z ? bk2 : bq2;
    void*        C   = z ? (void*)kfr : (void*)qbb;
    const float  sc  = z ? 1.f : qscale;
    const int    om  = z ? 2 : 0;
    gemm_core<64, 64, 0>(A, B, bia, C, sc, 0, om, 4, 256, 1024, blockIdx.x);
}

// Output projection -> f32. ONE call site.
__global__ __launch_bounds__(256) void gemmok(
    const short* __restrict__ xbb, const short* __restrict__ Wot,
    const float* __restrict__ bo, float* __restrict__ out)
{
    gemm_core<64, 64, 0>(xbb, Wot, bo, out, 1.f, 0, 1, 8, 512, 512, blockIdx.x);
}

// ---------------------------------------------------------------------------
// Flash attention — R3 proven form, verbatim (73 µs, VGPR 64, conflicts 0).
// ---------------------------------------------------------------------------
__global__ __launch_bounds__(256, 4) void flash_ks(
    const short* __restrict__ qb, const short* __restrict__ kfr,
    const short* __restrict__ vfr, short* __restrict__ xbb)
{
    const int L = blockIdx.x;          // 0..1023
    const int xcd = L & 7;
    const int idx = L >> 3;            // 0..127
    const int bh = xcd * 2 + (idx & 1);
    const int qt = idx >> 1;           // 0..63: 64 q rows per block
    const int b = bh >> 3, h = bh & 7;
    const int w = threadIdx.x >> 6;
    const int qg = w >> 1;             // q-group 0/1 (32 rows each)
    const int kh = w & 1;              // key-half 0/1
    const int lane = threadIdx.x & 63;
    const int l31 = lane & 31;
    const int half = lane >> 5;

    // smem is ONLY the end-combine: redO [2][32][66] f32 + redl [4][32] f32
    __shared__ __align__(16) char smem[17408];

    const short* qrow = qb + (size_t)(b * 4096 + qt * 64 + qg * 32 + l31) * 256 + h * 32 + half * 8;
    bf16x8 qf0 = __builtin_bit_cast(bf16x8, *(const short8*)(const void*)qrow);
    bf16x8 qf1 = __builtin_bit_cast(bf16x8, *(const short8*)(const void*)(qrow + 16));

    f32x16 O0{}, O1{};
    f32x2 lp = (f32x2){0.f, 0.f};      // denominator pair-accumulator (f32)

    const short* kbase = kfr + ((size_t)bh * 64) * 4 * 512 + lane * 8;
    const short* vbase = vfr + ((size_t)bh * 64) * 8 * 512 + lane * 8;

#pragma unroll 1
    for (int t = 0; t < 32; ++t) {
        const int kt = kh * 32 + t;
        bf16x8 kc[4], vc[8];
        const short* kp = kbase + (size_t)kt * 4 * 512;
        const short* vp = vbase + (size_t)kt * 8 * 512;
#pragma unroll
        for (int c = 0; c < 4; ++c)
            kc[c] = __builtin_bit_cast(bf16x8, *(const short8*)(const void*)(kp + c * 512));
#pragma unroll
        for (int c = 0; c < 8; ++c)
            vc[c] = __builtin_bit_cast(bf16x8, *(const short8*)(const void*)(vp + c * 512));

        f32x16 zero{};
        f32x16 s0 = __builtin_amdgcn_mfma_f32_32x32x16_bf16(kc[0], qf0, zero, 0, 0, 0);
        s0 = __builtin_amdgcn_mfma_f32_32x32x16_bf16(kc[1], qf1, s0, 0, 0, 0);
        f32x16 s1 = __builtin_amdgcn_mfma_f32_32x32x16_bf16(kc[2], qf0, zero, 0, 0, 0);
        s1 = __builtin_amdgcn_mfma_f32_32x32x16_bf16(kc[3], qf1, s1, 0, 0, 0);

        // exp + RNE cvt_pk pack + in-register cross-half redistribution;
        // denominator accumulated as f32 pair-sums (consistent w/ RNE pack).
        bf16x8 pf[4];
#pragma unroll
        for (int nt = 0; nt < 2; ++nt) {
            const f32x16& s = nt ? s1 : s0;
            float p0  = __builtin_amdgcn_exp2f(s[0]);
            float p1  = __builtin_amdgcn_exp2f(s[1]);
            float p2  = __builtin_amdgcn_exp2f(s[2]);
            float p3  = __builtin_amdgcn_exp2f(s[3]);
            float p4  = __builtin_amdgcn_exp2f(s[4]);
            float p5  = __builtin_amdgcn_exp2f(s[5]);
            float p6  = __builtin_amdgcn_exp2f(s[6]);
            float p7  = __builtin_amdgcn_exp2f(s[7]);
            float p8  = __builtin_amdgcn_exp2f(s[8]);
            float p9  = __builtin_amdgcn_exp2f(s[9]);
            float p10 = __builtin_amdgcn_exp2f(s[10]);
            float p11 = __builtin_amdgcn_exp2f(s[11]);
            float p12 = __builtin_amdgcn_exp2f(s[12]);
            float p13 = __builtin_amdgcn_exp2f(s[13]);
            float p14 = __builtin_amdgcn_exp2f(s[14]);
            float p15 = __builtin_amdgcn_exp2f(s[15]);

            lp += (f32x2){p0,  p1};
            lp += (f32x2){p2,  p3};
            lp += (f32x2){p4,  p5};
            lp += (f32x2){p6,  p7};
            lp += (f32x2){p8,  p9};
            lp += (f32x2){p10, p11};
            lp += (f32x2){p12, p13};
            lp += (f32x2){p14, p15};

            unsigned D0, D1, D2, D3, D4, D5, D6, D7;
            asm("v_cvt_pk_bf16_f32 %0, %1, %2" : "=v"(D0) : "v"(p0),  "v"(p1));
            asm("v_cvt_pk_bf16_f32 %0, %1, %2" : "=v"(D1) : "v"(p2),  "v"(p3));
            asm("v_cvt_pk_bf16_f32 %0, %1, %2" : "=v"(D2) : "v"(p4),  "v"(p5));
            asm("v_cvt_pk_bf16_f32 %0, %1, %2" : "=v"(D3) : "v"(p6),  "v"(p7));
            asm("v_cvt_pk_bf16_f32 %0, %1, %2" : "=v"(D4) : "v"(p8),  "v"(p9));
            asm("v_cvt_pk_bf16_f32 %0, %1, %2" : "=v"(D5) : "v"(p10), "v"(p11));
            asm("v_cvt_pk_bf16_f32 %0, %1, %2" : "=v"(D6) : "v"(p12), "v"(p13));
            asm("v_cvt_pk_bf16_f32 %0, %1, %2" : "=v"(D7) : "v"(p14), "v"(p15));
            // vdst_hi <-> src0_lo swaps: after these, (D0,D1,D2,D3) are the
            // 4 dwords of frag ks=2nt, (D4,D5,D6,D7) the dwords of ks=2nt+1.
            asm("v_permlane32_swap_b32 %0, %1" : "+v"(D0), "+v"(D2));
            asm("v_permlane32_swap_b32 %0, %1" : "+v"(D1), "+v"(D3));
            asm("v_permlane32_swap_b32 %0, %1" : "+v"(D4), "+v"(D6));
            asm("v_permlane32_swap_b32 %0, %1" : "+v"(D5), "+v"(D7));
            uint4v u0; u0[0] = D0; u0[1] = D1; u0[2] = D2; u0[3] = D3;
            uint4v u1; u1[0] = D4; u1[1] = D5; u1[2] = D6; u1[3] = D7;
            pf[2 * nt + 0] = __builtin_bit_cast(bf16x8, u0);
            pf[2 * nt + 1] = __builtin_bit_cast(bf16x8, u1);
        }

#pragma unroll
        for (int ks = 0; ks < 4; ++ks) {
            O0 = __builtin_amdgcn_mfma_f32_32x32x16_bf16(pf[ks], vc[ks], O0, 0, 0, 0);
            O1 = __builtin_amdgcn_mfma_f32_32x32x16_bf16(pf[ks], vc[4 + ks], O1, 0, 0, 0);
        }
    }

    // denominator: combine pair-accumulator, then lane halves (h0 + h1).
    float lsum = lp[0] + lp[1];
    float lother = lsum;
    asm("v_permlane32_swap_b32 %0, %1" : "+v"(lsum), "+v"(lother));
    lsum += lother;                    // full per-(qg,kh) sum, every lane

    // ---- combine key-half pairs per q-group ----
    float* redO = (float*)smem;              // [qg][32 q][66] = 16896 B
    float* redl = (float*)(smem + 16896);    // [qg*2+kh][32 q] = 512 B
    if (half == 0)
        redl[(qg * 2 + kh) * 32 + l31] = lsum;
    if (kh == 1) {
        float* Bo = redO + qg * 32 * 66;
#pragma unroll
        for (int r = 0; r < 16; ++r) {
            int q = (r & 3) + 8 * (r >> 2) + 4 * half;
            Bo[q * 66 + l31] = O0[r];
            Bo[q * 66 + 32 + l31] = O1[r];
        }
    }
    __syncthreads();
    if (kh == 0) {
        const float* Bo = redO + qg * 32 * 66;
#pragma unroll
        for (int r = 0; r < 16; ++r) {
            int q = (r & 3) + 8 * (r >> 2) + 4 * half;
            float o0 = O0[r] + Bo[q * 66 + l31];
            float o1 = O1[r] + Bo[q * 66 + 32 + l31];
            float inv = 1.f / (redl[(qg * 2 + 0) * 32 + q] + redl[(qg * 2 + 1) * 32 + q]);
            size_t row = (size_t)(b * 4096 + qt * 64 + qg * 32 + q);
            short* d = xbb + row * 512 + h * 64 + l31;
            d[0] = f2bf(o0 * inv);
            d[32] = f2bf(o1 * inv);
        }
    }
}

// ---------------------------------------------------------------------------
extern "C" void kernel_launch(void* const* d_in, const int* in_sizes, int n_in,
                              void* d_out, int out_size, void* d_ws, size_t ws_size,
                              hipStream_t stream)
{
    const float* query = (const float*)d_in[0];
    const float* key   = (const float*)d_in[1];
    const float* value = (const float*)d_in[2];
    const float* Wq1   = (const float*)d_in[3];
    const float* bq1   = (const float*)d_in[4];
    const float* Wq2   = (const float*)d_in[5];
    const float* bq2   = (const float*)d_in[6];
    const float* Wk1   = (const float*)d_in[7];
    const float* bk1   = (const float*)d_in[8];
    const float* Wk2   = (const float*)d_in[9];
    const float* bk2   = (const float*)d_in[10];
    const float* Wv    = (const float*)d_in[11];
    const float* bv    = (const float*)d_in[12];
    const float* Wo    = (const float*)d_in[13];
    const float* bo    = (const float*)d_in[14];
    float* out = (float*)d_out;

    // Workspace (bytes), overlays:
    char* ws = (char*)d_ws;
    short* H1q   = (short*)(ws + 0);          // 16 MB
    short* H1k   = (short*)(ws + 16777216);   // 16 MB
    short* xbb   = (short*)(ws + 0);          // overlay (H1 dead after gemm2)
    short* qbb   = (short*)(ws + 33554432);   // 4 MB
    short* kfr   = (short*)(ws + 50331648);   // 4 MB
    short* vfr   = (short*)(ws + 54525952);   // 8 MB
    short* Wq1t  = (short*)(ws + 62914560);
    short* Wk1t  = (short*)(ws + 63963136);
    short* Wq2t  = (short*)(ws + 65011712);
    short* Wk2t  = (short*)(ws + 65536000);
    short* Wvt   = (short*)(ws + 66060288);
    short* Wot   = (short*)(ws + 66584576);   // 512 KB -> end 67,108,864

    dim3 blk(256);
    const float qscale = 0.17677669529663687f * 1.4426950408889634f;

    // weight transposes
    prep_w<<<dim3(2048), blk, 0, stream>>>(
        Wq1, Wk1, Wq2, Wk2, Wv, Wo, Wq1t, Wk1t, Wq2t, Wk2t, Wvt, Wot);

    // merged front-end: q-MLP1 / k-MLP1 / v-projection in one dispatch
    mega1<<<dim3(512, 1, 3), blk, 0, stream>>>(
        query, key, value, Wq1t, Wk1t, Wvt, bq1, bk1, bv, H1q, H1k, vfr);

    // MLP layer 2 (q & k): q -> qbb (pre-scaled), k -> kfr scatter
    gemm2k<<<dim3(512, 1, 2), blk, 0, stream>>>(
        H1q, H1k, Wq2t, Wk2t, bq2, bk2, qbb, kfr, qscale);

    // attention
    flash_ks<<<dim3(1024), blk, 0, stream>>>(qbb, kfr, vfr, xbb);

    // output projection -> f32
    gemmok<<<dim3(1024), blk, 0, stream>>>(xbb, Wot, bo, out);
}

// Round 11
// 257.623 us; speedup vs baseline: 1.1728x; 1.1728x over previous
//
#include <hip/hip_runtime.h>
#include <math.h>

typedef __attribute__((ext_vector_type(8))) short short8;
typedef __bf16 bf16x8 __attribute__((ext_vector_type(8)));
typedef __attribute__((ext_vector_type(4))) float f32x4;
typedef __attribute__((ext_vector_type(2))) float f32x2;
typedef __attribute__((ext_vector_type(16))) float f32x16;
typedef __attribute__((ext_vector_type(4))) unsigned uint4v;

__device__ inline short f2bf(float f) {
    unsigned u = __builtin_bit_cast(unsigned, f);
    u += 0x7fff + ((u >> 16) & 1);   // round-to-nearest-even
    return (short)(u >> 16);
}
__device__ inline float gelu_f(float x) {
    return 0.5f * x * (1.f + erff(x * 0.70710678118654752f));
}

// global->LDS direct DMA, 16B per lane. Dest is wave-uniform base; HW writes
// base + lane*16. Source address is per-lane (pre-swizzled for XOR layout).
__device__ inline void gload_lds16(const void* g, void* l) {
    __builtin_amdgcn_global_load_lds(
        (const __attribute__((address_space(1))) unsigned int*)g,
        (__attribute__((address_space(3))) unsigned int*)l, 16, 0, 0);
}

// ---------------------------------------------------------------------------
// Weight prep only. 2048 blocks, all 6 weight transposes to bf16 [N][K].
// ---------------------------------------------------------------------------
__global__ __launch_bounds__(256) void prep_w(
    const float* __restrict__ Wq1, const float* __restrict__ Wk1,
    const float* __restrict__ Wq2, const float* __restrict__ Wk2,
    const float* __restrict__ Wv,  const float* __restrict__ Wo,
    short* __restrict__ Wq1t, short* __restrict__ Wk1t,
    short* __restrict__ Wq2t, short* __restrict__ Wk2t,
    short* __restrict__ Wvt,  short* __restrict__ Wot)
{
    int id = blockIdx.x;
    const float* W; short* Wt; int K, N;
    if (id < 512)       { W = Wq1; Wt = Wq1t; K = 512;  N = 1024; }
    else if (id < 1024) { W = Wk1; Wt = Wk1t; K = 512;  N = 1024; id -= 512; }
    else if (id < 1280) { W = Wq2; Wt = Wq2t; K = 1024; N = 256;  id -= 1024; }
    else if (id < 1536) { W = Wk2; Wt = Wk2t; K = 1024; N = 256;  id -= 1280; }
    else if (id < 1792) { W = Wv;  Wt = Wvt;  K = 512;  N = 512;  id -= 1536; }
    else                { W = Wo;  Wt = Wot;  K = 512;  N = 512;  id -= 1792; }
    int nx = N >> 5;
    int n0 = (id % nx) * 32, k0 = (id / nx) * 32;

    __shared__ float T[32][33];
    int tid = threadIdx.x;
    int r = tid >> 3, c4 = (tid & 7) * 4;
    float4 v4 = *(const float4*)&W[(size_t)(k0 + r) * N + n0 + c4];
    T[r][c4 + 0] = v4.x; T[r][c4 + 1] = v4.y; T[r][c4 + 2] = v4.z; T[r][c4 + 3] = v4.w;
    __syncthreads();
    short4 o;
    o.x = f2bf(T[c4 + 0][r]);
    o.y = f2bf(T[c4 + 1][r]);
    o.z = f2bf(T[c4 + 2][r]);
    o.w = f2bf(T[c4 + 3][r]);
    *(short4*)&Wt[(size_t)(n0 + r) * K + k0 + c4] = o;
}

// ---------------------------------------------------------------------------
// Shared GEMM core — 2-phase prefetch with STATIC double buffers (R10 fix:
// runtime-indexed As[buf] defeated LDS alias analysis -> compiler inserted
// vmcnt(0) before the compute-phase ds_reads -> full latency exposure.
// Distinct named arrays As0/As1/Bs0/Bs1 + pair-unrolled loop keep every LDS
// access statically disambiguated; the only vmem drain is the compiler's
// vmcnt(0) at the barrier, AFTER compute). ntile = K/64 is always even.
// 64x64 tiles: 4 x 8 KB = 32 KB LDS (same as proven R6 footprint).
// om: 0 = bf16 plain, 1 = f32 plain, 2 = kfr frag scatter, 3 = vfr frag
// scatter (exact inverses of the former repack_kv mappings, proven R6).
// AF32: A is raw f32 -> reg prefetch + v_cvt_pk_bf16_f32 (RNE) -> ds_write.
// Exactly ONE call site per __global__ kernel (R7/R8 lesson).
// ---------------------------------------------------------------------------
template <int BM, int BN, int AF32>
__device__ __forceinline__ void gemm_core(
    const void* __restrict__ A, const short* __restrict__ B,
    const float* __restrict__ bias, void* __restrict__ C_,
    float scale, int act, int om, int nbn, int N, int K, int L)
{
    constexpr int MT = BM / 32;
    constexpr int NT = BN / 32;
    const int xcd = L & 7;
    const int per = L >> 3;
    const int bn = (per % nbn) * BN;
    const int bm = ((per / nbn) * 8 + xcd) * BM;

    const int tid = threadIdx.x;
    const int w = tid >> 6;
    const int lane = tid & 63;
    const int l15 = lane & 15, quad = lane >> 4;
    const int wm = (w >> 1) * (BM / 2), wn = (w & 1) * (BN / 2);

    __shared__ __align__(16) short As0[BM * 64], As1[BM * 64];
    __shared__ __align__(16) short Bs0[BN * 64], Bs1[BN * 64];

    const float* Af = (const float*)A;
    const short* Ab = (const short*)A;

    float4 xa[BM / 32], ya[BM / 32];   // AF32 in-flight reg staging

    auto issue = [&](int k0, short* Asb, short* Bsb) {
#pragma unroll
        for (int i = 0; i < BM / 32; ++i) {
            int ga = tid + i * 256;
            int row = ga >> 3, g = ga & 7;
            if constexpr (AF32) {
                const float* src = &Af[(size_t)(bm + row) * K + k0 + ((g ^ (row & 7)) * 8)];
                xa[i] = *(const float4*)src;
                ya[i] = *(const float4*)(src + 4);
            } else {
                gload_lds16(&Ab[(size_t)(bm + row) * K + k0 + ((g ^ (row & 7)) * 8)],
                            &Asb[(i * 256 + w * 64) * 8]);
            }
        }
#pragma unroll
        for (int i = 0; i < BN / 32; ++i) {
            int gb = tid + i * 256;
            int row = gb >> 3, g = gb & 7;
            gload_lds16(&B[(size_t)(bn + row) * K + k0 + ((g ^ (row & 7)) * 8)],
                        &Bsb[(i * 256 + w * 64) * 8]);
        }
    };
    auto finishA = [&](short* Asb) {
        if constexpr (AF32) {
#pragma unroll
            for (int i = 0; i < BM / 32; ++i) {
                int ga = tid + i * 256;
                int row = ga >> 3, g = ga & 7;
                unsigned u0, u1, u2, u3;
                asm("v_cvt_pk_bf16_f32 %0, %1, %2" : "=v"(u0) : "v"(xa[i].x), "v"(xa[i].y));
                asm("v_cvt_pk_bf16_f32 %0, %1, %2" : "=v"(u1) : "v"(xa[i].z), "v"(xa[i].w));
                asm("v_cvt_pk_bf16_f32 %0, %1, %2" : "=v"(u2) : "v"(ya[i].x), "v"(ya[i].y));
                asm("v_cvt_pk_bf16_f32 %0, %1, %2" : "=v"(u3) : "v"(ya[i].z), "v"(ya[i].w));
                uint4v u; u[0] = u0; u[1] = u1; u[2] = u2; u[3] = u3;
                *(uint4v*)(void*)&Asb[row * 64 + g * 8] = u;
            }
        }
    };

    f32x4 acc[MT][NT];
#pragma unroll
    for (int mt = 0; mt < MT; ++mt)
#pragma unroll
        for (int nt = 0; nt < NT; ++nt) acc[mt][nt] = (f32x4){0.f, 0.f, 0.f, 0.f};

    auto compute = [&](const short* Asc, const short* Bsc) {
#pragma unroll
        for (int ks = 0; ks < 2; ++ks) {
            bf16x8 af[MT], bfr[NT];
#pragma unroll
            for (int t2 = 0; t2 < MT; ++t2) {
                int row = wm + t2 * 16 + l15;
                af[t2] = __builtin_bit_cast(bf16x8,
                    *(const short8*)(const void*)&Asc[row * 64 + (((ks * 4 + quad) ^ (row & 7)) * 8)]);
            }
#pragma unroll
            for (int t2 = 0; t2 < NT; ++t2) {
                int row = wn + t2 * 16 + l15;
                bfr[t2] = __builtin_bit_cast(bf16x8,
                    *(const short8*)(const void*)&Bsc[row * 64 + (((ks * 4 + quad) ^ (row & 7)) * 8)]);
            }
#pragma unroll
            for (int mt = 0; mt < MT; ++mt)
#pragma unroll
                for (int nt = 0; nt < NT; ++nt)
                    acc[mt][nt] = __builtin_amdgcn_mfma_f32_16x16x32_bf16(af[mt], bfr[nt], acc[mt][nt], 0, 0, 0);
        }
    };

    const int ntile = K >> 6;   // 8 or 16: always even

    issue(0, As0, Bs0);
    finishA(As0);
    __syncthreads();

    for (int t = 0; t < ntile; t += 2) {
        issue((t + 1) << 6, As1, Bs1);       // always valid: ntile even
        compute(As0, Bs0);
        finishA(As1);
        __syncthreads();
        if (t + 2 < ntile) issue((t + 2) << 6, As0, Bs0);
        compute(As1, Bs1);
        if (t + 2 < ntile) finishA(As0);
        __syncthreads();
    }

    float bvv[NT];
#pragma unroll
    for (int nt = 0; nt < NT; ++nt) bvv[nt] = bias[bn + wn + nt * 16 + l15];
#pragma unroll
    for (int mt = 0; mt < MT; ++mt)
#pragma unroll
        for (int r = 0; r < 4; ++r) {
            int row = bm + wm + mt * 16 + quad * 4 + r;
#pragma unroll
            for (int nt = 0; nt < NT; ++nt) {
                float v = acc[mt][nt][r] + bvv[nt];
                if (act) v = gelu_f(v);
                v *= scale;
                int col = bn + wn + nt * 16 + l15;
                if (om == 1) {
                    ((float*)C_)[(size_t)row * N + col] = v;
                } else if (om == 2) {
                    // kfr scatter: inverse of repack_kv K-path.
                    int b_ = row >> 12, key = row & 4095;
                    int kt = key >> 6, nt_ = (key >> 5) & 1, l31_ = key & 31;
                    int h_ = col >> 5, kcol = col & 31;
                    int ks_ = kcol >> 4, hi_ = (kcol >> 3) & 1, j_ = kcol & 7;
                    size_t idx = ((((size_t)(b_ * 8 + h_) * 64 + kt) * 4 +
                                   (nt_ * 2 + ks_)) * 64 + (hi_ * 32 + l31_)) * 8 + j_;
                    ((short*)C_)[idx] = f2bf(v);
                } else if (om == 3) {
                    // vfr scatter: inverse of repack_kv V-path.
                    int b_ = row >> 12, key = row & 4095;
                    int kt = key >> 6, keyr = key & 63;
                    int ks_ = keyr >> 4, hi_ = (keyr >> 3) & 1, j_ = keyr & 7;
                    int h_ = col >> 6, dk = col & 63;
                    int dt_ = dk >> 5, l31_ = dk & 31;
                    size_t idx = ((((size_t)(b_ * 8 + h_) * 64 + kt) * 8 +
                                   (dt_ * 4 + ks_)) * 64 + (hi_ * 32 + l31_)) * 8 + j_;
                    ((short*)C_)[idx] = f2bf(v);
                } else {
                    ((short*)C_)[(size_t)row * N + col] = f2bf(v);
                }
            }
        }
}

// ---------------------------------------------------------------------------
// Merged front-end: z=0 q-MLP1, z=1 k-MLP1 (N=1024, GELU), z=2 v-projection
// (N=512, vfr scatter). All 64x64 tiles, AF32 staging; ONE gemm_core call
// site. z=2 uses only 1024 of the 2048 launched blocks.
// ---------------------------------------------------------------------------
__global__ __launch_bounds__(256) void mega1(
    const float* __restrict__ q, const float* __restrict__ k,
    const float* __restrict__ v,
    const short* __restrict__ Wq1t, const short* __restrict__ Wk1t,
    const short* __restrict__ Wvt,
    const float* __restrict__ bq1, const float* __restrict__ bk1,
    const float* __restrict__ bv,
    short* __restrict__ H1q, short* __restrict__ H1k, short* __restrict__ vfr)
{
    const int z = blockIdx.z;
    if (z == 2 && blockIdx.x >= 1024) return;
    const float* A   = z == 2 ? v    : (z == 1 ? k    : q);
    const short* B   = z == 2 ? Wvt  : (z == 1 ? Wk1t : Wq1t);
    const float* bia = z == 2 ? bv   : (z == 1 ? bk1  : bq1);
    void*        C   = z == 2 ? (void*)vfr : (z == 1 ? (void*)H1k : (void*)H1q);
    const int act = z == 2 ? 0 : 1;
    const int om  = z == 2 ? 3 : 0;
    const int nbn = z == 2 ? 8 : 16;
    const int N   = z == 2 ? 512 : 1024;
    gemm_core<64, 64, 1>(A, B, bia, C, 1.f, act, om, nbn, N, 512, blockIdx.x);
}

// MLP layer 2 (q & k): q -> qbb plain (pre-scaled), k -> kfr frag scatter.
// ONE gemm_core call site.
__global__ __launch_bounds__(256) void gemm2k(
    const short* __restrict__ H1q, const short* __restrict__ H1k,
    const short* __restrict__ Wq2t, const short* __restrict__ Wk2t,
    const float* __restrict__ bq2, const float* __restrict__ bk2,
    short* __restrict__ qbb, short* __restrict__ kfr, float qscale)
{
    const int z = blockIdx.z;
    const short* A   = z ? H1k : H1q;
    const short* B   = z ? Wk2t : Wq2t;
    const float* bia = z ? bk2 : bq2;
    void*        C   = z ? (void*)kfr : (void*)qbb;
    const float  sc  = z ? 1.f : qscale;
    const int    om  = z ? 2 : 0;
    gemm_core<64, 64, 0>(A, B, bia, C, sc, 0, om, 4, 256, 1024, blockIdx.x);
}

// Output projection -> f32. ONE call site.
__global__ __launch_bounds__(256) void gemmok(
    const short* __restrict__ xbb, const short* __restrict__ Wot,
    const float* __restrict__ bo, float* __restrict__ out)
{
    gemm_core<64, 64, 0>(xbb, Wot, bo, out, 1.f, 0, 1, 8, 512, 512, blockIdx.x);
}

// ---------------------------------------------------------------------------
// Flash attention — R3 proven form, verbatim (73 µs, VGPR 64, conflicts 0).
// ---------------------------------------------------------------------------
__global__ __launch_bounds__(256, 4) void flash_ks(
    const short* __restrict__ qb, const short* __restrict__ kfr,
    const short* __restrict__ vfr, short* __restrict__ xbb)
{
    const int L = blockIdx.x;          // 0..1023
    const int xcd = L & 7;
    const int idx = L >> 3;            // 0..127
    const int bh = xcd * 2 + (idx & 1);
    const int qt = idx >> 1;           // 0..63: 64 q rows per block
    const int b = bh >> 3, h = bh & 7;
    const int w = threadIdx.x >> 6;
    const int qg = w >> 1;             // q-group 0/1 (32 rows each)
    const int kh = w & 1;              // key-half 0/1
    const int lane = threadIdx.x & 63;
    const int l31 = lane & 31;
    const int half = lane >> 5;

    // smem is ONLY the end-combine: redO [2][32][66] f32 + redl [4][32] f32
    __shared__ __align__(16) char smem[17408];

    const short* qrow = qb + (size_t)(b * 4096 + qt * 64 + qg * 32 + l31) * 256 + h * 32 + half * 8;
    bf16x8 qf0 = __builtin_bit_cast(bf16x8, *(const short8*)(const void*)qrow);
    bf16x8 qf1 = __builtin_bit_cast(bf16x8, *(const short8*)(const void*)(qrow + 16));

    f32x16 O0{}, O1{};
    f32x2 lp = (f32x2){0.f, 0.f};      // denominator pair-accumulator (f32)

    const short* kbase = kfr + ((size_t)bh * 64) * 4 * 512 + lane * 8;
    const short* vbase = vfr + ((size_t)bh * 64) * 8 * 512 + lane * 8;

#pragma unroll 1
    for (int t = 0; t < 32; ++t) {
        const int kt = kh * 32 + t;
        bf16x8 kc[4], vc[8];
        const short* kp = kbase + (size_t)kt * 4 * 512;
        const short* vp = vbase + (size_t)kt * 8 * 512;
#pragma unroll
        for (int c = 0; c < 4; ++c)
            kc[c] = __builtin_bit_cast(bf16x8, *(const short8*)(const void*)(kp + c * 512));
#pragma unroll
        for (int c = 0; c < 8; ++c)
            vc[c] = __builtin_bit_cast(bf16x8, *(const short8*)(const void*)(vp + c * 512));

        f32x16 zero{};
        f32x16 s0 = __builtin_amdgcn_mfma_f32_32x32x16_bf16(kc[0], qf0, zero, 0, 0, 0);
        s0 = __builtin_amdgcn_mfma_f32_32x32x16_bf16(kc[1], qf1, s0, 0, 0, 0);
        f32x16 s1 = __builtin_amdgcn_mfma_f32_32x32x16_bf16(kc[2], qf0, zero, 0, 0, 0);
        s1 = __builtin_amdgcn_mfma_f32_32x32x16_bf16(kc[3], qf1, s1, 0, 0, 0);

        // exp + RNE cvt_pk pack + in-register cross-half redistribution;
        // denominator accumulated as f32 pair-sums (consistent w/ RNE pack).
        bf16x8 pf[4];
#pragma unroll
        for (int nt = 0; nt < 2; ++nt) {
            const f32x16& s = nt ? s1 : s0;
            float p0  = __builtin_amdgcn_exp2f(s[0]);
            float p1  = __builtin_amdgcn_exp2f(s[1]);
            float p2  = __builtin_amdgcn_exp2f(s[2]);
            float p3  = __builtin_amdgcn_exp2f(s[3]);
            float p4  = __builtin_amdgcn_exp2f(s[4]);
            float p5  = __builtin_amdgcn_exp2f(s[5]);
            float p6  = __builtin_amdgcn_exp2f(s[6]);
            float p7  = __builtin_amdgcn_exp2f(s[7]);
            float p8  = __builtin_amdgcn_exp2f(s[8]);
            float p9  = __builtin_amdgcn_exp2f(s[9]);
            float p10 = __builtin_amdgcn_exp2f(s[10]);
            float p11 = __builtin_amdgcn_exp2f(s[11]);
            float p12 = __builtin_amdgcn_exp2f(s[12]);
            float p13 = __builtin_amdgcn_exp2f(s[13]);
            float p14 = __builtin_amdgcn_exp2f(s[14]);
            float p15 = __builtin_amdgcn_exp2f(s[15]);

            lp += (f32x2){p0,  p1};
            lp += (f32x2){p2,  p3};
            lp += (f32x2){p4,  p5};
            lp += (f32x2){p6,  p7};
            lp += (f32x2){p8,  p9};
            lp += (f32x2){p10, p11};
            lp += (f32x2){p12, p13};
            lp += (f32x2){p14, p15};

            unsigned D0, D1, D2, D3, D4, D5, D6, D7;
            asm("v_cvt_pk_bf16_f32 %0, %1, %2" : "=v"(D0) : "v"(p0),  "v"(p1));
            asm("v_cvt_pk_bf16_f32 %0, %1, %2" : "=v"(D1) : "v"(p2),  "v"(p3));
            asm("v_cvt_pk_bf16_f32 %0, %1, %2" : "=v"(D2) : "v"(p4),  "v"(p5));
            asm("v_cvt_pk_bf16_f32 %0, %1, %2" : "=v"(D3) : "v"(p6),  "v"(p7));
            asm("v_cvt_pk_bf16_f32 %0, %1, %2" : "=v"(D4) : "v"(p8),  "v"(p9));
            asm("v_cvt_pk_bf16_f32 %0, %1, %2" : "=v"(D5) : "v"(p10), "v"(p11));
            asm("v_cvt_pk_bf16_f32 %0, %1, %2" : "=v"(D6) : "v"(p12), "v"(p13));
            asm("v_cvt_pk_bf16_f32 %0, %1, %2" : "=v"(D7) : "v"(p14), "v"(p15));
            // vdst_hi <-> src0_lo swaps: after these, (D0,D1,D2,D3) are the
            // 4 dwords of frag ks=2nt, (D4,D5,D6,D7) the dwords of ks=2nt+1.
            asm("v_permlane32_swap_b32 %0, %1" : "+v"(D0), "+v"(D2));
            asm("v_permlane32_swap_b32 %0, %1" : "+v"(D1), "+v"(D3));
            asm("v_permlane32_swap_b32 %0, %1" : "+v"(D4), "+v"(D6));
            asm("v_permlane32_swap_b32 %0, %1" : "+v"(D5), "+v"(D7));
            uint4v u0; u0[0] = D0; u0[1] = D1; u0[2] = D2; u0[3] = D3;
            uint4v u1; u1[0] = D4; u1[1] = D5; u1[2] = D6; u1[3] = D7;
            pf[2 * nt + 0] = __builtin_bit_cast(bf16x8, u0);
            pf[2 * nt + 1] = __builtin_bit_cast(bf16x8, u1);
        }

#pragma unroll
        for (int ks = 0; ks < 4; ++ks) {
            O0 = __builtin_amdgcn_mfma_f32_32x32x16_bf16(pf[ks], vc[ks], O0, 0, 0, 0);
            O1 = __builtin_amdgcn_mfma_f32_32x32x16_bf16(pf[ks], vc[4 + ks], O1, 0, 0, 0);
        }
    }

    // denominator: combine pair-accumulator, then lane halves (h0 + h1).
    float lsum = lp[0] + lp[1];
    float lother = lsum;
    asm("v_permlane32_swap_b32 %0, %1" : "+v"(lsum), "+v"(lother));
    lsum += lother;                    // full per-(qg,kh) sum, every lane

    // ---- combine key-half pairs per q-group ----
    float* redO = (float*)smem;              // [qg][32 q][66] = 16896 B
    float* redl = (float*)(smem + 16896);    // [qg*2+kh][32 q] = 512 B
    if (half == 0)
        redl[(qg * 2 + kh) * 32 + l31] = lsum;
    if (kh == 1) {
        float* Bo = redO + qg * 32 * 66;
#pragma unroll
        for (int r = 0; r < 16; ++r) {
            int q = (r & 3) + 8 * (r >> 2) + 4 * half;
            Bo[q * 66 + l31] = O0[r];
            Bo[q * 66 + 32 + l31] = O1[r];
        }
    }
    __syncthreads();
    if (kh == 0) {
        const float* Bo = redO + qg * 32 * 66;
#pragma unroll
        for (int r = 0; r < 16; ++r) {
            int q = (r & 3) + 8 * (r >> 2) + 4 * half;
            float o0 = O0[r] + Bo[q * 66 + l31];
            float o1 = O1[r] + Bo[q * 66 + 32 + l31];
            float inv = 1.f / (redl[(qg * 2 + 0) * 32 + q] + redl[(qg * 2 + 1) * 32 + q]);
            size_t row = (size_t)(b * 4096 + qt * 64 + qg * 32 + q);
            short* d = xbb + row * 512 + h * 64 + l31;
            d[0] = f2bf(o0 * inv);
            d[32] = f2bf(o1 * inv);
        }
    }
}

// ---------------------------------------------------------------------------
extern "C" void kernel_launch(void* const* d_in, const int* in_sizes, int n_in,
                              void* d_out, int out_size, void* d_ws, size_t ws_size,
                              hipStream_t stream)
{
    const float* query = (const float*)d_in[0];
    const float* key   = (const float*)d_in[1];
    const float* value = (const float*)d_in[2];
    const float* Wq1   = (const float*)d_in[3];
    const float* bq1   = (const float*)d_in[4];
    const float* Wq2   = (const float*)d_in[5];
    const float* bq2   = (const float*)d_in[6];
    const float* Wk1   = (const float*)d_in[7];
    const float* bk1   = (const float*)d_in[8];
    const float* Wk2   = (const float*)d_in[9];
    const float* bk2   = (const float*)d_in[10];
    const float* Wv    = (const float*)d_in[11];
    const float* bv    = (const float*)d_in[12];
    const float* Wo    = (const float*)d_in[13];
    const float* bo    = (const float*)d_in[14];
    float* out = (float*)d_out;

    // Workspace (bytes), overlays:
    char* ws = (char*)d_ws;
    short* H1q   = (short*)(ws + 0);          // 16 MB
    short* H1k   = (short*)(ws + 16777216);   // 16 MB
    short* xbb   = (short*)(ws + 0);          // overlay (H1 dead after gemm2)
    short* qbb   = (short*)(ws + 33554432);   // 4 MB
    short* kfr   = (short*)(ws + 50331648);   // 4 MB
    short* vfr   = (short*)(ws + 54525952);   // 8 MB
    short* Wq1t  = (short*)(ws + 62914560);
    short* Wk1t  = (short*)(ws + 63963136);
    short* Wq2t  = (short*)(ws + 65011712);
    short* Wk2t  = (short*)(ws + 65536000);
    short* Wvt   = (short*)(ws + 66060288);
    short* Wot   = (short*)(ws + 66584576);   // 512 KB -> end 67,108,864

    dim3 blk(256);
    const float qscale = 0.17677669529663687f * 1.4426950408889634f;

    // weight transposes
    prep_w<<<dim3(2048), blk, 0, stream>>>(
        Wq1, Wk1, Wq2, Wk2, Wv, Wo, Wq1t, Wk1t, Wq2t, Wk2t, Wvt, Wot);

    // merged front-end: q-MLP1 / k-MLP1 / v-projection in one dispatch
    mega1<<<dim3(2048, 1, 3), blk, 0, stream>>>(
        query, key, value, Wq1t, Wk1t, Wvt, bq1, bk1, bv, H1q, H1k, vfr);

    // MLP layer 2 (q & k): q -> qbb (pre-scaled), k -> kfr scatter
    gemm2k<<<dim3(512, 1, 2), blk, 0, stream>>>(
        H1q, H1k, Wq2t, Wk2t, bq2, bk2, qbb, kfr, qscale);

    // attention
    flash_ks<<<dim3(1024), blk, 0, stream>>>(qbb, kfr, vfr, xbb);

    // output projection -> f32
    gemmok<<<dim3(1024), blk, 0, stream>>>(xbb, Wot, bo, out);
}